// Round 9
// baseline (1317.081 us; speedup 1.0000x reference)
//
#include <hip/hip_runtime.h>
#include <stdint.h>

typedef unsigned long long u64;
typedef unsigned int u32;
typedef _Float16 f16;
typedef _Float16 f16x8 __attribute__((ext_vector_type(8)));
typedef float f32x4 __attribute__((ext_vector_type(4)));
typedef u32 u32x4 __attribute__((ext_vector_type(4)));

#define NA 261888          // anchors per batch image
#define CAP 4096           // candidate cap for top-k sort
#define SCALE_CLAMP 4.135166556742356f
#define NBLK_IMG 684       // conv tiles per image (32x4 px tiles)

// ---- workspace offsets (bytes) ----
#define WT_OFF   0              // f16 wHL: 2 planes x 589824 = 2,359,296 B
#define BOX_OFF  2359296        // 2*NA*4*4        = 8,380,416
#define SB_OFF   10739712       // 2*NA*4          = 2,095,104
#define HIST_OFF 12834816       // coarse hist 2*4096*4 = 32768
#define FINE_OFF 12867584       // 2*16*4 = 128
#define META_OFF 13359104       // 64 (T, C*, above, -, then cnt[2])
#define CAND_OFF 13359168       // 2*CAP*8         = 65,536
#define TOP_OFF  13424704       // 2*1000*4*4      = 32,000
#define MASK_OFF 13456704       // 2*1000*16*8     = 256,000
#define NH_OFF   13712704       // NHWC split-f16: 174592 px * 1024 B = 178,782,208
#define WS_NEED  192494912ull

// LDS (float idx) epilogue layout — IDENTICAL to R7 (frozen numerics contract:
// head logit = [2 co-half partials, nf 0..7 asc fma chain, xor(1,2,4,8) tree,
// 2-contributor atomicAdd] + bias added last at decode).
#define E_WH   0        // 15*256
#define E_HB   3840     // 16
#define E_PART 3872     // 2*15*64 = 1920
#define BUFB   26112    // bytes per patch buffer (204 rows * 128B)

// ---- weight prep: conv_w [co][ci][ky][kx] f32 -> wHL[sp][kyx][cib][co][ci8] f16 ----
__global__ void k_wprep(const float* __restrict__ w, f16* __restrict__ wHL) {
    int i = blockIdx.x * 256 + threadIdx.x;
    if (i >= 589824) return;
    int co = i / 2304, rem = i % 2304;
    int ci = rem / 9, kyx = rem % 9;
    float v = w[i];
    f16 h = (f16)v;
    f16 lo = (f16)(v - (float)h);
    u32 idx = (u32)((kyx * 32 + (ci >> 3)) * 256 + co) * 8 + (ci & 7);
    wHL[idx] = h;
    wHL[589824 + idx] = lo;
}

// ---- NCHW f32 -> chunk-major NHWC split-f16 ----
__global__ __launch_bounds__(256) void k_nhwc(
    const float* __restrict__ p2, const float* __restrict__ p3,
    const float* __restrict__ p4, const float* __restrict__ p5,
    const float* __restrict__ p6, unsigned char* __restrict__ nh)
{
    int t = blockIdx.x * 256 + threadIdx.x;
    if (t >= 1396736) return;
    int n = t / 698368;
    int r = t % 698368;
    int lvl, c, pxy, HW, cumpx;
    const float* in;
    if (r < 524288)      { lvl = 0; HW = 65536; cumpx = 0;     c = r >> 16; pxy = r & 65535; in = p2; }
    else if (r < 655360) { lvl = 1; HW = 16384; cumpx = 65536; r -= 524288; c = r >> 14; pxy = r & 16383; in = p3; }
    else if (r < 688128) { lvl = 2; HW = 4096;  cumpx = 81920; r -= 655360; c = r >> 12; pxy = r & 4095;  in = p4; }
    else if (r < 696320) { lvl = 3; HW = 1024;  cumpx = 86016; r -= 688128; c = r >> 10; pxy = r & 1023;  in = p5; }
    else                 { lvl = 4; HW = 256;   cumpx = 87040; r -= 696320; c = r >> 8;  pxy = r & 255;   in = p6; }
    (void)lvl;
    const float* gp = in + ((size_t)n * 256 + (size_t)c * 32) * HW + pxy;
    u32 hi[16], lo[16];
#pragma unroll
    for (int k = 0; k < 16; ++k) {
        float v0 = gp[(size_t)(2 * k) * HW];
        float v1 = gp[(size_t)(2 * k + 1) * HW];
        f16 h0 = (f16)v0, h1 = (f16)v1;
        f16 e0 = (f16)(v0 - (float)h0), e1 = (f16)(v1 - (float)h1);
        hi[k] = ((u32)__builtin_bit_cast(unsigned short, h1) << 16) |
                 (u32)__builtin_bit_cast(unsigned short, h0);
        lo[k] = ((u32)__builtin_bit_cast(unsigned short, e1) << 16) |
                 (u32)__builtin_bit_cast(unsigned short, e0);
    }
    unsigned char* dst = nh + ((size_t)n * 87296 + (size_t)cumpx) * 1024
                            + ((size_t)c * HW + (size_t)pxy) * 128;
    u32x4* d4 = (u32x4*)dst;
#pragma unroll
    for (int i = 0; i < 4; ++i)
        d4[i] = (u32x4){hi[4 * i], hi[4 * i + 1], hi[4 * i + 2], hi[4 * i + 3]};
#pragma unroll
    for (int i = 0; i < 4; ++i)
        d4[4 + i] = (u32x4){lo[4 * i], lo[4 * i + 1], lo[4 * i + 2], lo[4 * i + 3]};
}

// ---- fused split-f16 MFMA conv3x3 + relu + heads + decode (R7 numerics verbatim) ----
// Only change vs R7: double-buffered LDS patch + register-staged write-late prefetch.
__global__ __launch_bounds__(256, 2) void k_conv_nh(
    const unsigned char* __restrict__ nh, const f16* __restrict__ wHL,
    const float* __restrict__ cb, const float* __restrict__ ow,
    const float* __restrict__ ob, const float* __restrict__ dw_,
    const float* __restrict__ db_, u32* __restrict__ scoreb,
    float* __restrict__ boxes)
{
    __shared__ __align__(16) float smf[13056];   // 2 x 26112 B patch buffers / epilogue
    char* smemc = (char*)smf;

    int tid = threadIdx.x;
    int bid = blockIdx.x;
    int ebid = (bid & 7) * 171 + (bid >> 3);     // XCD-contiguous tile mapping (1368 = 8*171)
    int n = ebid / NBLK_IMG;
    int tb = ebid % NBLK_IMG;
    int lvl, t0, cumpx;
    if      (tb < 512) { lvl = 0; t0 = tb;       cumpx = 0;     }
    else if (tb < 640) { lvl = 1; t0 = tb - 512; cumpx = 65536; }
    else if (tb < 672) { lvl = 2; t0 = tb - 640; cumpx = 81920; }
    else if (tb < 680) { lvl = 3; t0 = tb - 672; cumpx = 86016; }
    else               { lvl = 4; t0 = tb - 680; cumpx = 87040; }
    int H = 256 >> lvl, W = H;
    int HW = H * W;
    int xtiles = (W >= 32) ? (W >> 5) : 1;
    int xt = t0 % xtiles, yt = t0 / xtiles;
    int tx0 = xt * 32, ty0 = yt * 4;
    const unsigned char* nhb = nh + ((size_t)n * 87296 + (size_t)cumpx) * 1024;

    int l = tid & 63;
    int wid = tid >> 6;
    int wm = wid >> 1, wn = wid & 1;
    int lr = l & 15;       // frag row / col lane
    int lg = l >> 4;       // k-quarter group

    // staging geometry (chunk-invariant): 1632 16B segments = 204 px x 8 segs
    int srcoff[7], dstoff[7];
#pragma unroll
    for (int w = 0; w < 7; ++w) {
        int flat = w * 256 + tid;
        int px = flat >> 3, seg = flat & 7;
        int dy = px / 34, dx = px % 34;
        int y = ty0 + dy - 1, x = tx0 + dx - 1;
        bool part = flat < 1632;
        bool inb = part && y >= 0 && y < H && x >= 0 && x < W;
        dstoff[w] = part ? (px * 128 + ((seg * 16) ^ ((px & 7) << 4))) : -1;
        srcoff[w] = inb ? ((y * W + x) * 128 + seg * 16) : -1;
    }

    f32x4 acc[4][8];
#pragma unroll
    for (int mi = 0; mi < 4; ++mi)
#pragma unroll
        for (int nf = 0; nf < 8; ++nf) acc[mi][nf] = (f32x4){0.f, 0.f, 0.f, 0.f};

    const f16* wHp = wHL;
    const f16* wLp = wHL + 589824;

    // prologue: stage chunk 0 into buffer 0
    u32x4 st[7];
#pragma unroll
    for (int w = 0; w < 7; ++w) {
        st[w] = (u32x4){0u, 0u, 0u, 0u};
        if (srcoff[w] >= 0) st[w] = *(const u32x4*)(nhb + srcoff[w]);
    }
#pragma unroll
    for (int w = 0; w < 7; ++w)
        if (dstoff[w] >= 0) *(u32x4*)(smemc + dstoff[w]) = st[w];

    for (int chunk = 0; chunk < 8; ++chunk) {
        // T14: issue next chunk's loads; latency hides under this chunk's compute
        if (chunk < 7) {
            const unsigned char* cb2 = nhb + (size_t)(chunk + 1) * HW * 128;
#pragma unroll
            for (int w = 0; w < 7; ++w) {
                st[w] = (u32x4){0u, 0u, 0u, 0u};
                if (srcoff[w] >= 0) st[w] = *(const u32x4*)(cb2 + srcoff[w]);
            }
        }
        __syncthreads();   // buf[chunk&1] writes visible; prev-buffer reads all done
        int cb_ = (chunk & 1) * BUFB;

        for (int kyx = 0; kyx < 9; ++kyx) {
            int ky = kyx / 3, kx = kyx % 3;
            f16x8 aH[4], aL[4];
#pragma unroll
            for (int mi = 0; mi < 4; ++mi) {
                int q = (2 * wm + (mi >> 1) + ky) * 34 + (mi & 1) * 16 + kx + lr;
                int sw = (q & 7) << 4;
                int rb = cb_ + q * 128;
                aH[mi] = *(const f16x8*)(smemc + rb + ((lg * 16) ^ sw));
                aL[mi] = *(const f16x8*)(smemc + rb + ((64 + lg * 16) ^ sw));
            }
            u32 kbase = (u32)(kyx * 32 + chunk * 4 + lg) * 256;
#pragma unroll
            for (int h = 0; h < 2; ++h) {
                f16x8 bH[4], bL[4];
#pragma unroll
                for (int j = 0; j < 4; ++j) {
                    int nf = h * 4 + j;
                    u32 ei = (kbase + (u32)(wn * 128 + nf * 16 + lr)) * 8;
                    bH[j] = *(const f16x8*)(wHp + ei);
                    bL[j] = *(const f16x8*)(wLp + ei);
                }
#pragma unroll
                for (int j = 0; j < 4; ++j) {
#pragma unroll
                    for (int mi = 0; mi < 4; ++mi) {
                        f32x4 c = acc[mi][h * 4 + j];
                        c = __builtin_amdgcn_mfma_f32_16x16x32_f16(aH[mi], bH[j], c, 0, 0, 0);
                        c = __builtin_amdgcn_mfma_f32_16x16x32_f16(aH[mi], bL[j], c, 0, 0, 0);
                        c = __builtin_amdgcn_mfma_f32_16x16x32_f16(aL[mi], bH[j], c, 0, 0, 0);
                        acc[mi][h * 4 + j] = c;
                    }
                }
            }
        }
        // write staged regs into the other buffer (read next iteration)
        if (chunk < 7) {
            int nb = ((chunk + 1) & 1) * BUFB;
#pragma unroll
            for (int w = 0; w < 7; ++w)
                if (dstoff[w] >= 0) *(u32x4*)(smemc + nb + dstoff[w]) = st[w];
        }
    }

    // ---- epilogue: R7 VERBATIM (frozen head-sum numerics) ----
    __syncthreads();
    for (int j = tid; j < 3840; j += 256) {
        int o = j >> 8, co = j & 255;
        smf[E_WH + j] = (o < 3) ? ow[o * 256 + co] : dw_[(o - 3) * 256 + co];
    }
    if (tid < 15) smf[E_HB + tid] = (tid < 3) ? ob[tid] : db_[tid - 3];
    for (int j = tid; j < 1920; j += 256) smf[E_PART + j] = 0.f;

    float cbv[8];
#pragma unroll
    for (int nf = 0; nf < 8; ++nf) cbv[nf] = cb[wn * 128 + nf * 16 + lr];
    __syncthreads();

#pragma unroll
    for (int mi = 0; mi < 4; ++mi)
#pragma unroll
        for (int nf = 0; nf < 8; ++nf)
#pragma unroll
            for (int e = 0; e < 4; ++e)
                acc[mi][nf][e] = fmaxf(acc[mi][nf][e] + cbv[nf], 0.f);

    for (int o = 0; o < 15; ++o) {
        float wv[8];
#pragma unroll
        for (int nf = 0; nf < 8; ++nf) wv[nf] = smf[E_WH + o * 256 + wn * 128 + nf * 16 + lr];
#pragma unroll
        for (int mi = 0; mi < 4; ++mi) {
#pragma unroll
            for (int e = 0; e < 4; ++e) {
                float s = 0.f;
#pragma unroll
                for (int nf = 0; nf < 8; ++nf) s = fmaf(wv[nf], acc[mi][nf][e], s);
                s += __shfl_xor(s, 1);
                s += __shfl_xor(s, 2);
                s += __shfl_xor(s, 4);
                s += __shfl_xor(s, 8);
                if (lr == 0)
                    atomicAdd(&smf[E_PART + (wm * 15 + o) * 64 + mi * 16 + lg * 4 + e], s);
            }
        }
    }
    __syncthreads();

    if ((l & 63) < 32) {
        int px = wn * 32 + (l & 31);
        int yy = 2 * wm + (px >> 5);
        int gx = tx0 + (px & 31);
        int gy = ty0 + yy;
        if (gx < W) {
            int aOff = (lvl == 0) ? 0 : (lvl == 1) ? 196608 : (lvl == 2) ? 245760 : (lvl == 3) ? 258048 : 261120;
            float size = (float)(32 << lvl);
            float stride = (float)(4 << lvl);
            float cxa = gx * stride, cya = gy * stride;
#pragma unroll
            for (int a = 0; a < 3; ++a) {
                float lgt = smf[E_PART + (wm * 15 + a) * 64 + px] + smf[E_HB + a];
                float dxv = smf[E_PART + (wm * 15 + 3 + a * 4 + 0) * 64 + px] + smf[E_HB + 3 + a * 4 + 0];
                float dyv = smf[E_PART + (wm * 15 + 3 + a * 4 + 1) * 64 + px] + smf[E_HB + 3 + a * 4 + 1];
                float dwv = smf[E_PART + (wm * 15 + 3 + a * 4 + 2) * 64 + px] + smf[E_HB + 3 + a * 4 + 2];
                float dhv = smf[E_PART + (wm * 15 + 3 + a * 4 + 3) * 64 + px] + smf[E_HB + 3 + a * 4 + 3];
                float r = (a == 0) ? 0.5f : (a == 1) ? 1.0f : 2.0f;
                float wa = sqrtf(size * size / r);
                float ha = wa * r;
                dwv = fminf(dwv, SCALE_CLAMP);
                dhv = fminf(dhv, SCALE_CLAMP);
                float cx = dxv * wa + cxa, cy = dyv * ha + cya;
                float w_ = expf(dwv) * wa, h_ = expf(dhv) * ha;
                float x1 = fminf(fmaxf(cx - 0.5f * w_, 0.f), 1024.f);
                float y1 = fminf(fmaxf(cy - 0.5f * h_, 0.f), 1024.f);
                float x2 = fminf(fmaxf(cx + 0.5f * w_, 0.f), 1024.f);
                float y2 = fminf(fmaxf(cy + 0.5f * h_, 0.f), 1024.f);
                double sc = 1.0 / (1.0 + exp(-(double)lgt));
                u32 bits = __float_as_uint((float)sc);
                int gi = aOff + (gy * W + gx) * 3 + a;
                scoreb[(size_t)n * NA + gi] = bits;
                float* bp = boxes + ((size_t)n * NA + gi) * 4;
                bp[0] = x1; bp[1] = y1; bp[2] = x2; bp[3] = y2;
            }
        }
    }
}

// ---- fallback conv (R4 verbatim): NCHW staging + T14 prefetch ----
__global__ __launch_bounds__(256, 2) void k_conv_legacy(
    const float* __restrict__ p2, const float* __restrict__ p3,
    const float* __restrict__ p4, const float* __restrict__ p5,
    const float* __restrict__ p6, const f16* __restrict__ wHL,
    const float* __restrict__ cb, const float* __restrict__ ow,
    const float* __restrict__ ob, const float* __restrict__ dw_,
    const float* __restrict__ db_, u32* __restrict__ scoreb,
    float* __restrict__ boxes)
{
    __shared__ __align__(16) float smf[6528];
    char* smemc = (char*)smf;

    int tid = threadIdx.x;
    int bid = blockIdx.x;
    int n = bid / NBLK_IMG;
    int tb = bid % NBLK_IMG;
    int lvl, t0;
    if      (tb < 512) { lvl = 0; t0 = tb;       }
    else if (tb < 640) { lvl = 1; t0 = tb - 512; }
    else if (tb < 672) { lvl = 2; t0 = tb - 640; }
    else if (tb < 680) { lvl = 3; t0 = tb - 672; }
    else               { lvl = 4; t0 = tb - 680; }
    int H = 256 >> lvl, W = H;
    int HW = H * W;
    int xtiles = (W >= 32) ? (W >> 5) : 1;
    int xt = t0 % xtiles, yt = t0 / xtiles;
    int tx0 = xt * 32, ty0 = yt * 4;
    const float* in = (lvl == 0) ? p2 : (lvl == 1) ? p3 : (lvl == 2) ? p4 : (lvl == 3) ? p5 : p6;
    in += (size_t)n * 256 * HW;

    int l = tid & 63;
    int wid = tid >> 6;
    int wm = wid >> 1, wn = wid & 1;
    int lr = l & 15;
    int lg = l >> 4;

    int off[13];
#pragma unroll
    for (int w = 0; w < 13; ++w) {
        int idx = w * 256 + tid;
        int ci2 = idx / 204, p = idx % 204;
        int dy = p / 34, dx = p % 34;
        int y = ty0 + dy - 1, x = tx0 + dx - 1;
        bool inb = (idx < 3264) && y >= 0 && y < H && x >= 0 && x < W;
        off[w] = inb ? (ci2 * 2 * HW + y * W + x) : -1;
    }

    float rv0[13], rv1[13];
#pragma unroll
    for (int w = 0; w < 13; ++w) {
        rv0[w] = 0.f; rv1[w] = 0.f;
        if (off[w] >= 0) { const float* gp = in + off[w]; rv0[w] = gp[0]; rv1[w] = gp[HW]; }
    }

    f32x4 acc[4][8];
#pragma unroll
    for (int mi = 0; mi < 4; ++mi)
#pragma unroll
        for (int nf = 0; nf < 8; ++nf) acc[mi][nf] = (f32x4){0.f, 0.f, 0.f, 0.f};

    const f16* wHp = wHL;
    const f16* wLp = wHL + 589824;

    for (int chunk = 0; chunk < 8; ++chunk) {
        __syncthreads();
#pragma unroll
        for (int w = 0; w < 13; ++w) {
            int idx = w * 256 + tid;
            if (idx < 3264) {
                int ci2 = idx / 204, p = idx % 204;
                f16 h0 = (f16)rv0[w], h1 = (f16)rv1[w];
                f16 e0 = (f16)(rv0[w] - (float)h0), e1 = (f16)(rv1[w] - (float)h1);
                u32 hp = ((u32)__builtin_bit_cast(unsigned short, h1) << 16) |
                          (u32)__builtin_bit_cast(unsigned short, h0);
                u32 lp = ((u32)__builtin_bit_cast(unsigned short, e1) << 16) |
                          (u32)__builtin_bit_cast(unsigned short, e0);
                int sw = (p & 7) << 4;
                int rb = p * 128;
                *(u32*)(smemc + rb + ((ci2 * 4) ^ sw)) = hp;
                *(u32*)(smemc + rb + ((64 + ci2 * 4) ^ sw)) = lp;
            }
        }
        if (chunk < 7) {
            const float* cbase = in + (size_t)(chunk + 1) * 32 * HW;
#pragma unroll
            for (int w = 0; w < 13; ++w) {
                rv0[w] = 0.f; rv1[w] = 0.f;
                if (off[w] >= 0) { const float* gp = cbase + off[w]; rv0[w] = gp[0]; rv1[w] = gp[HW]; }
            }
        }
        __syncthreads();

        for (int kyx = 0; kyx < 9; ++kyx) {
            int ky = kyx / 3, kx = kyx % 3;
            f16x8 aH[4], aL[4];
#pragma unroll
            for (int mi = 0; mi < 4; ++mi) {
                int q = (2 * wm + (mi >> 1) + ky) * 34 + (mi & 1) * 16 + kx + lr;
                int sw = (q & 7) << 4;
                int rb = q * 128;
                aH[mi] = *(const f16x8*)(smemc + rb + ((lg * 16) ^ sw));
                aL[mi] = *(const f16x8*)(smemc + rb + ((64 + lg * 16) ^ sw));
            }
            u32 kbase = (u32)(kyx * 32 + chunk * 4 + lg) * 256;
#pragma unroll
            for (int h = 0; h < 2; ++h) {
                f16x8 bH[4], bL[4];
#pragma unroll
                for (int j = 0; j < 4; ++j) {
                    int nf = h * 4 + j;
                    u32 ei = (kbase + (u32)(wn * 128 + nf * 16 + lr)) * 8;
                    bH[j] = *(const f16x8*)(wHp + ei);
                    bL[j] = *(const f16x8*)(wLp + ei);
                }
#pragma unroll
                for (int j = 0; j < 4; ++j) {
#pragma unroll
                    for (int mi = 0; mi < 4; ++mi) {
                        f32x4 c = acc[mi][h * 4 + j];
                        c = __builtin_amdgcn_mfma_f32_16x16x32_f16(aH[mi], bH[j], c, 0, 0, 0);
                        c = __builtin_amdgcn_mfma_f32_16x16x32_f16(aH[mi], bL[j], c, 0, 0, 0);
                        c = __builtin_amdgcn_mfma_f32_16x16x32_f16(aL[mi], bH[j], c, 0, 0, 0);
                        acc[mi][h * 4 + j] = c;
                    }
                }
            }
        }
    }

    __syncthreads();
    for (int j = tid; j < 3840; j += 256) {
        int o = j >> 8, co = j & 255;
        smf[E_WH + j] = (o < 3) ? ow[o * 256 + co] : dw_[(o - 3) * 256 + co];
    }
    if (tid < 15) smf[E_HB + tid] = (tid < 3) ? ob[tid] : db_[tid - 3];
    for (int j = tid; j < 1920; j += 256) smf[E_PART + j] = 0.f;

    float cbv[8];
#pragma unroll
    for (int nf = 0; nf < 8; ++nf) cbv[nf] = cb[wn * 128 + nf * 16 + lr];
    __syncthreads();

#pragma unroll
    for (int mi = 0; mi < 4; ++mi)
#pragma unroll
        for (int nf = 0; nf < 8; ++nf)
#pragma unroll
            for (int e = 0; e < 4; ++e)
                acc[mi][nf][e] = fmaxf(acc[mi][nf][e] + cbv[nf], 0.f);

    for (int o = 0; o < 15; ++o) {
        float wv[8];
#pragma unroll
        for (int nf = 0; nf < 8; ++nf) wv[nf] = smf[E_WH + o * 256 + wn * 128 + nf * 16 + lr];
#pragma unroll
        for (int mi = 0; mi < 4; ++mi) {
#pragma unroll
            for (int e = 0; e < 4; ++e) {
                float s = 0.f;
#pragma unroll
                for (int nf = 0; nf < 8; ++nf) s = fmaf(wv[nf], acc[mi][nf][e], s);
                s += __shfl_xor(s, 1);
                s += __shfl_xor(s, 2);
                s += __shfl_xor(s, 4);
                s += __shfl_xor(s, 8);
                if (lr == 0)
                    atomicAdd(&smf[E_PART + (wm * 15 + o) * 64 + mi * 16 + lg * 4 + e], s);
            }
        }
    }
    __syncthreads();

    if ((l & 63) < 32) {
        int px = wn * 32 + (l & 31);
        int yy = 2 * wm + (px >> 5);
        int gx = tx0 + (px & 31);
        int gy = ty0 + yy;
        if (gx < W) {
            int aOff = (lvl == 0) ? 0 : (lvl == 1) ? 196608 : (lvl == 2) ? 245760 : (lvl == 3) ? 258048 : 261120;
            float size = (float)(32 << lvl);
            float stride = (float)(4 << lvl);
            float cxa = gx * stride, cya = gy * stride;
#pragma unroll
            for (int a = 0; a < 3; ++a) {
                float lgt = smf[E_PART + (wm * 15 + a) * 64 + px] + smf[E_HB + a];
                float dxv = smf[E_PART + (wm * 15 + 3 + a * 4 + 0) * 64 + px] + smf[E_HB + 3 + a * 4 + 0];
                float dyv = smf[E_PART + (wm * 15 + 3 + a * 4 + 1) * 64 + px] + smf[E_HB + 3 + a * 4 + 1];
                float dwv = smf[E_PART + (wm * 15 + 3 + a * 4 + 2) * 64 + px] + smf[E_HB + 3 + a * 4 + 2];
                float dhv = smf[E_PART + (wm * 15 + 3 + a * 4 + 3) * 64 + px] + smf[E_HB + 3 + a * 4 + 3];
                float r = (a == 0) ? 0.5f : (a == 1) ? 1.0f : 2.0f;
                float wa = sqrtf(size * size / r);
                float ha = wa * r;
                dwv = fminf(dwv, SCALE_CLAMP);
                dhv = fminf(dhv, SCALE_CLAMP);
                float cx = dxv * wa + cxa, cy = dyv * ha + cya;
                float w_ = expf(dwv) * wa, h_ = expf(dhv) * ha;
                float x1 = fminf(fmaxf(cx - 0.5f * w_, 0.f), 1024.f);
                float y1 = fminf(fmaxf(cy - 0.5f * h_, 0.f), 1024.f);
                float x2 = fminf(fmaxf(cx + 0.5f * w_, 0.f), 1024.f);
                float y2 = fminf(fmaxf(cy + 0.5f * h_, 0.f), 1024.f);
                double sc = 1.0 / (1.0 + exp(-(double)lgt));
                u32 bits = __float_as_uint((float)sc);
                int gi = aOff + (gy * W + gx) * 3 + a;
                scoreb[(size_t)n * NA + gi] = bits;
                float* bp = boxes + ((size_t)n * NA + gi) * 4;
                bp[0] = x1; bp[1] = y1; bp[2] = x2; bp[3] = y2;
            }
        }
    }
}

// -------------------- coarse histogram (b>>20), LDS-privatized --------------------
__global__ __launch_bounds__(256) void k_histc(const u32* __restrict__ scoreb,
                                               u32* __restrict__ histc) {
    __shared__ u32 lh[4096];
    for (int j = threadIdx.x; j < 4096; j += 256) lh[j] = 0;
    __syncthreads();
    int n = blockIdx.x >> 6;
    int blk = blockIdx.x & 63;
    const u32* sb = scoreb + (size_t)n * NA;
    for (int i = blk * 256 + threadIdx.x; i < NA; i += 64 * 256)
        atomicAdd(&lh[sb[i] >> 20], 1u);
    __syncthreads();
    for (int j = threadIdx.x; j < 4096; j += 256) {
        u32 v = lh[j];
        if (v) atomicAdd(&histc[n * 4096 + j], v);
    }
}

// -------------------- find coarse crossing bin C* + countAbove --------------------
__global__ void k_scanc(const u32* __restrict__ histc, u32* __restrict__ meta) {
    int n = blockIdx.x, tid = threadIdx.x;
    __shared__ u32 cs[256];
    u32 s = 0;
    for (int j = 0; j < 16; ++j) s += histc[n * 4096 + (4095 - (tid * 16 + j))];
    cs[tid] = s;
    __syncthreads();
    if (tid == 0) {
        u32 cum = 0;
        for (int t = 0; t < 256; ++t) {
            if (cum + cs[t] >= 1000u) {
                u32 c2 = cum;
                for (int d = t * 16;; ++d) {
                    int bin = 4095 - d;
                    u32 h = histc[n * 4096 + bin];
                    if (c2 + h >= 1000u) { meta[n * 4 + 1] = (u32)bin; meta[n * 4 + 2] = c2; break; }
                    c2 += h;
                }
                break;
            }
            cum += cs[t];
        }
    }
}

// -------------------- exact 16-sub-bin refine inside C* --------------------
__global__ void k_fine(const u32* __restrict__ scoreb, const u32* __restrict__ meta,
                       u32* __restrict__ fineh) {
    __shared__ u32 lf[32];
    if (threadIdx.x < 32) lf[threadIdx.x] = 0;
    __syncthreads();
    u32 C0 = meta[1], C1 = meta[5];
    int stridex = gridDim.x * blockDim.x;
    for (int i = blockIdx.x * blockDim.x + threadIdx.x; i < 2 * NA; i += stridex) {
        u32 b = scoreb[i];
        int n = (i >= NA);
        if ((b >> 20) == (n ? C1 : C0)) atomicAdd(&lf[n * 16 + ((b >> 16) & 15)], 1u);
    }
    __syncthreads();
    if (threadIdx.x < 32) {
        u32 v = lf[threadIdx.x];
        if (v) atomicAdd(&fineh[threadIdx.x], v);
    }
}

// -------------------- exact 16-bit threshold T --------------------
__global__ void k_scanf(const u32* __restrict__ fineh, u32* __restrict__ meta) {
    int n = threadIdx.x;
    if (n < 2) {
        u32 cum = meta[n * 4 + 2];
        u32 C = meta[n * 4 + 1];
        u32 T = C << 4;
        for (int f = 15; f >= 0; --f) {
            cum += fineh[n * 16 + f];
            if (cum >= 1000u) { T = (C << 4) | (u32)f; break; }
        }
        meta[n * 4] = T;
    }
}

// -------------------- compact candidates >= threshold bin --------------------
__global__ void k_compact(const u32* __restrict__ scoreb, const u32* __restrict__ meta,
                          u32* __restrict__ cnt, u64* __restrict__ cand) {
    int stridex = gridDim.x * blockDim.x;
    for (int i = blockIdx.x * blockDim.x + threadIdx.x; i < 2 * NA; i += stridex) {
        u32 b = scoreb[i];
        int n = (i >= NA);
        u32 T = meta[n * 4];
        if ((b >> 16) >= T) {
            u32 p = atomicAdd(&cnt[n], 1u);
            if (p < CAP)
                cand[n * CAP + p] = ((u64)(~b) << 32) | (u32)(i - n * NA);
        }
    }
}

// -------------------- bitonic sort candidates, gather top-1000 boxes --------------------
__global__ __launch_bounds__(512) void k_sort(const u64* __restrict__ cand,
                                              const u32* __restrict__ cnt,
                                              const float* __restrict__ boxes,
                                              float* __restrict__ topbox) {
    __shared__ u64 a[CAP];
    int n = blockIdx.x, tid = threadIdx.x;
    u32 C = cnt[n]; if (C > CAP) C = CAP;
    for (int i = tid; i < CAP; i += 512)
        a[i] = (i < (int)C) ? cand[n * CAP + i] : ~0ULL;
    __syncthreads();
    for (int k = 2; k <= CAP; k <<= 1) {
        for (int j = k >> 1; j > 0; j >>= 1) {
            for (int i = tid; i < CAP; i += 512) {
                int l = i ^ j;
                if (l > i) {
                    u64 x = a[i], y = a[l];
                    bool up = ((i & k) == 0);
                    if ((x > y) == up) { a[i] = y; a[l] = x; }
                }
            }
            __syncthreads();
        }
    }
    for (int r = tid; r < 1000; r += 512) {
        u32 idx = (u32)(a[r] & 0xFFFFFFFFu);
        const float* bp = boxes + ((size_t)n * NA + idx) * 4;
        float* tp = topbox + (n * 1000 + r) * 4;
        tp[0] = bp[0]; tp[1] = bp[1]; tp[2] = bp[2]; tp[3] = bp[3];
    }
}

// -------------------- NMS suppression bitmasks --------------------
__global__ __launch_bounds__(256) void k_mask(const float* __restrict__ topbox,
                                              u64* __restrict__ mask) {
    __shared__ float4 lb[1000];
    int n = blockIdx.x >> 2, sub = blockIdx.x & 3;
    for (int e = threadIdx.x; e < 1000; e += 256)
        lb[e] = ((const float4*)topbox)[n * 1000 + e];
    __syncthreads();
    int i = sub * 256 + threadIdx.x;
    if (i >= 1000) return;
    float4 b = lb[i];
    float area = (b.z - b.x) * (b.w - b.y);
    u64* mrow = mask + (size_t)(n * 1000 + i) * 16;
    for (int w = 0; w < 16; ++w) {
        u64 bits = 0;
        int j0 = w * 64;
        int jmax = 1000 - j0; if (jmax > 64) jmax = 64;
        for (int jb = 0; jb < jmax; ++jb) {
            int j = j0 + jb;
            if (j > i) {
                float4 c = lb[j];
                float ix1 = fmaxf(b.x, c.x), iy1 = fmaxf(b.y, c.y);
                float ix2 = fminf(b.z, c.z), iy2 = fminf(b.w, c.w);
                float iw = fmaxf(ix2 - ix1, 0.f), ih = fmaxf(iy2 - iy1, 0.f);
                float inter = iw * ih;
                float areac = (c.z - c.x) * (c.w - c.y);
                float iou = inter / fmaxf(area + areac - inter, 1e-6f);
                if (iou > 0.7f) bits |= (1ULL << jb);
            }
        }
        mrow[w] = bits;
    }
}

// -------------------- sequential sweep + stable partition + output --------------------
__global__ __launch_bounds__(256) void k_final(const float* __restrict__ topbox,
                                               const u64* __restrict__ mask,
                                               float* __restrict__ out) {
    __shared__ u64 kw[16];
    __shared__ u32 PL[17];
    int n = blockIdx.x, tid = threadIdx.x;
    if (tid < 64) {
        int lane = tid;
        u64 keep = 0;
        if (lane < 16) keep = (lane < 15) ? ~0ULL : ((1ULL << 40) - 1);
        const u64* mb = mask + (size_t)n * 16000;
        u64 rcur = mb[lane & 15];
        for (int i = 0; i < 1000; ++i) {
            u64 rnext = (i + 1 < 1000) ? mb[(size_t)(i + 1) * 16 + (lane & 15)] : 0ULL;
            int w = i >> 6;
            u64 kb = __shfl(keep, w, 64);
            if ((kb >> (i & 63)) & 1ULL) {
                if (lane < 16) keep &= ~rcur;
            }
            rcur = rnext;
        }
        if (lane < 16) kw[lane] = keep;
    }
    __syncthreads();
    if (tid == 0) {
        u32 c = 0;
        for (int w = 0; w < 16; ++w) { PL[w] = c; c += (u32)__popcll(kw[w]); }
        PL[16] = c;
    }
    __syncthreads();
    u32 NK = PL[16];
    for (int i = tid; i < 1000; i += 256) {
        int w = i >> 6, b = i & 63;
        u64 word = kw[w];
        bool kept = (word >> b) & 1ULL;
        u32 kb4 = PL[w] + (u32)__popcll(word & ((1ULL << b) - 1ULL));
        u32 pos = kept ? kb4 : NK + (u32)i - kb4;
        const float* bp = topbox + (n * 1000 + i) * 4;
        float x1 = kept ? bp[0] : 0.f;
        float y1 = kept ? bp[1] : 0.f;
        float x2 = kept ? bp[2] : 0.f;
        float y2 = kept ? bp[3] : 0.f;
        size_t rrow = (size_t)n * 1000 + pos;
        out[rrow * 5 + 0] = 0.f;
        out[rrow * 5 + 1] = x1; out[rrow * 5 + 2] = y1;
        out[rrow * 5 + 3] = x2; out[rrow * 5 + 4] = y2;
        float* dp = out + 10000 + rrow * 4;
        dp[0] = x1; dp[1] = y1; dp[2] = x2; dp[3] = y2;
    }
}

extern "C" void kernel_launch(void* const* d_in, const int* in_sizes, int n_in,
                              void* d_out, int out_size, void* d_ws, size_t ws_size,
                              hipStream_t stream) {
    const float* p2 = (const float*)d_in[0];
    const float* p3 = (const float*)d_in[1];
    const float* p4 = (const float*)d_in[2];
    const float* p5 = (const float*)d_in[3];
    const float* p6 = (const float*)d_in[4];
    const float* conv_w = (const float*)d_in[5];
    const float* conv_b = (const float*)d_in[6];
    const float* obj_w = (const float*)d_in[7];
    const float* obj_b = (const float*)d_in[8];
    const float* delta_w = (const float*)d_in[9];
    const float* delta_b = (const float*)d_in[10];
    char* ws = (char*)d_ws;

    f16*   wHL    = (f16*)  (ws + WT_OFF);
    float* boxes  = (float*)(ws + BOX_OFF);
    u32*   scoreb = (u32*)  (ws + SB_OFF);
    u32*   histc  = (u32*)  (ws + HIST_OFF);
    u32*   fineh  = (u32*)  (ws + FINE_OFF);
    u32*   meta   = (u32*)  (ws + META_OFF);
    u32*   cnt    = meta + 8;
    u64*   cand   = (u64*)  (ws + CAND_OFF);
    float* topbox = (float*)(ws + TOP_OFF);
    u64*   mask   = (u64*)  (ws + MASK_OFF);

    hipMemsetAsync(ws + HIST_OFF, 0, 32768 + 128, stream);
    hipMemsetAsync(ws + META_OFF, 0, 64, stream);

    k_wprep<<<2304, 256, 0, stream>>>(conv_w, wHL);

    if (ws_size >= WS_NEED) {
        unsigned char* nh = (unsigned char*)(ws + NH_OFF);
        k_nhwc<<<5456, 256, 0, stream>>>(p2, p3, p4, p5, p6, nh);
        k_conv_nh<<<2 * NBLK_IMG, 256, 0, stream>>>(nh, wHL, conv_b,
                                                    obj_w, obj_b, delta_w, delta_b,
                                                    scoreb, boxes);
    } else {
        k_conv_legacy<<<2 * NBLK_IMG, 256, 0, stream>>>(p2, p3, p4, p5, p6, wHL, conv_b,
                                                        obj_w, obj_b, delta_w, delta_b,
                                                        scoreb, boxes);
    }
    k_histc<<<128, 256, 0, stream>>>(scoreb, histc);
    k_scanc<<<2, 256, 0, stream>>>(histc, meta);
    k_fine<<<512, 256, 0, stream>>>(scoreb, meta, fineh);
    k_scanf<<<1, 64, 0, stream>>>(fineh, meta);
    k_compact<<<1024, 256, 0, stream>>>(scoreb, meta, cnt, cand);
    k_sort<<<2, 512, 0, stream>>>(cand, cnt, boxes, topbox);
    k_mask<<<8, 256, 0, stream>>>(topbox, mask);
    k_final<<<2, 256, 0, stream>>>(topbox, mask, (float*)d_out);
    (void)in_sizes; (void)n_in; (void)out_size; (void)ws_size;
}

// Round 10
// 1053.177 us; speedup vs baseline: 1.2506x; 1.2506x over previous
//
#include <hip/hip_runtime.h>
#include <stdint.h>

typedef unsigned long long u64;
typedef unsigned int u32;
typedef _Float16 f16;
typedef _Float16 f16x8 __attribute__((ext_vector_type(8)));
typedef float f32x4 __attribute__((ext_vector_type(4)));
typedef u32 u32x4 __attribute__((ext_vector_type(4)));

#define NA 261888          // anchors per batch image
#define CAP 4096           // candidate cap for top-k sort
#define SCALE_CLAMP 4.135166556742356f
#define NBLK_IMG 684       // conv tiles per image (32x4 px tiles)

// ---- workspace offsets (bytes) ----
#define WT_OFF   0              // f16 wHL: 2 planes x 589824 = 2,359,296 B
#define BOX_OFF  2359296        // 2*NA*4*4        = 8,380,416
#define SB_OFF   10739712       // 2*NA*4          = 2,095,104
#define HIST_OFF 12834816       // coarse hist 2*4096*4 = 32768
#define FINE_OFF 12867584       // 2*16*4 = 128
#define META_OFF 13359104       // 64 (T, C*, above, -, then cnt[2])
#define CAND_OFF 13359168       // 2*CAP*8         = 65,536
#define TOP_OFF  13424704       // 2*1000*4*4      = 32,000
#define MASK_OFF 13456704       // 2*1000*16*8     = 256,000
#define NH_OFF   13712704       // NHWC split-f16: 174592 px * 1024 B = 178,782,208
#define WS_NEED  192494912ull

// LDS (float idx) epilogue layout — IDENTICAL to R7 (frozen numerics contract:
// head logit = [2 co-half partials, nf 0..7 asc fma chain, xor(1,2,4,8) tree,
// 2-contributor atomicAdd] + bias added last at decode).
#define E_WH   0        // 15*256
#define E_HB   3840     // 16
#define E_PART 3872     // 2*15*64 = 1920
#define BUFB   26112    // bytes per patch buffer (204 rows * 128B = 1632 slots x 16B)

#define AS1C(p) ((const __attribute__((address_space(1))) void*)(p))
#define AS3(p)  ((__attribute__((address_space(3))) void*)(p))

// ---- weight prep: conv_w [co][ci][ky][kx] f32 -> wHL[sp][kyx][cib][co][ci8] f16 ----
__global__ void k_wprep(const float* __restrict__ w, f16* __restrict__ wHL) {
    int i = blockIdx.x * 256 + threadIdx.x;
    if (i >= 589824) return;
    int co = i / 2304, rem = i % 2304;
    int ci = rem / 9, kyx = rem % 9;
    float v = w[i];
    f16 h = (f16)v;
    f16 lo = (f16)(v - (float)h);
    u32 idx = (u32)((kyx * 32 + (ci >> 3)) * 256 + co) * 8 + (ci & 7);
    wHL[idx] = h;
    wHL[589824 + idx] = lo;
}

// ---- NCHW f32 -> chunk-major NHWC split-f16 ----
__global__ __launch_bounds__(256) void k_nhwc(
    const float* __restrict__ p2, const float* __restrict__ p3,
    const float* __restrict__ p4, const float* __restrict__ p5,
    const float* __restrict__ p6, unsigned char* __restrict__ nh)
{
    int t = blockIdx.x * 256 + threadIdx.x;
    if (t >= 1396736) return;
    int n = t / 698368;
    int r = t % 698368;
    int lvl, c, pxy, HW, cumpx;
    const float* in;
    if (r < 524288)      { lvl = 0; HW = 65536; cumpx = 0;     c = r >> 16; pxy = r & 65535; in = p2; }
    else if (r < 655360) { lvl = 1; HW = 16384; cumpx = 65536; r -= 524288; c = r >> 14; pxy = r & 16383; in = p3; }
    else if (r < 688128) { lvl = 2; HW = 4096;  cumpx = 81920; r -= 655360; c = r >> 12; pxy = r & 4095;  in = p4; }
    else if (r < 696320) { lvl = 3; HW = 1024;  cumpx = 86016; r -= 688128; c = r >> 10; pxy = r & 1023;  in = p5; }
    else                 { lvl = 4; HW = 256;   cumpx = 87040; r -= 696320; c = r >> 8;  pxy = r & 255;   in = p6; }
    (void)lvl;
    const float* gp = in + ((size_t)n * 256 + (size_t)c * 32) * HW + pxy;
    u32 hi[16], lo[16];
#pragma unroll
    for (int k = 0; k < 16; ++k) {
        float v0 = gp[(size_t)(2 * k) * HW];
        float v1 = gp[(size_t)(2 * k + 1) * HW];
        f16 h0 = (f16)v0, h1 = (f16)v1;
        f16 e0 = (f16)(v0 - (float)h0), e1 = (f16)(v1 - (float)h1);
        hi[k] = ((u32)__builtin_bit_cast(unsigned short, h1) << 16) |
                 (u32)__builtin_bit_cast(unsigned short, h0);
        lo[k] = ((u32)__builtin_bit_cast(unsigned short, e1) << 16) |
                 (u32)__builtin_bit_cast(unsigned short, e0);
    }
    unsigned char* dst = nh + ((size_t)n * 87296 + (size_t)cumpx) * 1024
                            + ((size_t)c * HW + (size_t)pxy) * 128;
    u32x4* d4 = (u32x4*)dst;
#pragma unroll
    for (int i = 0; i < 4; ++i)
        d4[i] = (u32x4){hi[4 * i], hi[4 * i + 1], hi[4 * i + 2], hi[4 * i + 3]};
#pragma unroll
    for (int i = 0; i < 4; ++i)
        d4[4 + i] = (u32x4){lo[4 * i], lo[4 * i + 1], lo[4 * i + 2], lo[4 * i + 3]};
}

// ---- fused split-f16 MFMA conv3x3 + relu + heads + decode (R7 numerics verbatim) ----
// Staging via async global_load_lds DMA (no staging VGPRs), double-buffered LDS,
// swizzle applied on the GLOBAL source address (LDS image byte-identical to R7).
__global__ __launch_bounds__(256, 2) void k_conv_nh(
    const unsigned char* __restrict__ nh, const f16* __restrict__ wHL,
    const float* __restrict__ cb, const float* __restrict__ ow,
    const float* __restrict__ ob, const float* __restrict__ dw_,
    const float* __restrict__ db_, u32* __restrict__ scoreb,
    float* __restrict__ boxes)
{
    __shared__ __align__(16) float smf[13056];   // 2 x 26112 B patch buffers / epilogue
    char* smemc = (char*)smf;

    int tid = threadIdx.x;
    int bid = blockIdx.x;
    int ebid = (bid & 7) * 171 + (bid >> 3);     // XCD-contiguous tile mapping (1368 = 8*171)
    int n = ebid / NBLK_IMG;
    int tb = ebid % NBLK_IMG;
    int lvl, t0, cumpx;
    if      (tb < 512) { lvl = 0; t0 = tb;       cumpx = 0;     }
    else if (tb < 640) { lvl = 1; t0 = tb - 512; cumpx = 65536; }
    else if (tb < 672) { lvl = 2; t0 = tb - 640; cumpx = 81920; }
    else if (tb < 680) { lvl = 3; t0 = tb - 672; cumpx = 86016; }
    else               { lvl = 4; t0 = tb - 680; cumpx = 87040; }
    int H = 256 >> lvl, W = H;
    int HW = H * W;
    int xtiles = (W >= 32) ? (W >> 5) : 1;
    int xt = t0 % xtiles, yt = t0 / xtiles;
    int tx0 = xt * 32, ty0 = yt * 4;
    const unsigned char* nhb = nh + ((size_t)n * 87296 + (size_t)cumpx) * 1024;

    int l = tid & 63;
    int wid = tid >> 6;
    int wm = wid >> 1, wn = wid & 1;
    int lr = l & 15;       // frag row / col lane
    int lg = l >> 4;       // k-quarter group

    // staging geometry (chunk-invariant): 1632 16B slots = 204 px x 8 segs.
    // LDS dest is LINEAR slot*16 (== wave-uniform base + lane*16); the XOR swizzle
    // is pre-applied to the global source seg so the LDS image matches R7 exactly.
    int srco[7];
#pragma unroll
    for (int w = 0; w < 7; ++w) {
        int flat = w * 256 + tid;
        int px = flat >> 3, seg = flat & 7;
        int dy = px / 34, dx = px % 34;
        int y = ty0 + dy - 1, x = tx0 + dx - 1;
        bool part = flat < 1632;
        bool inb = part && y >= 0 && y < H && x >= 0 && x < W;
        srco[w] = inb ? ((y * W + x) * 128 + ((seg * 16) ^ ((px & 7) << 4))) : -1;
    }

    // pre-zero OOB halo slots in BOTH buffers (DMA never writes them)
#pragma unroll
    for (int w = 0; w < 7; ++w) {
        int flat = w * 256 + tid;
        if (flat < 1632 && srco[w] < 0) {
            *(u32x4*)(smemc + flat * 16) = (u32x4){0u, 0u, 0u, 0u};
            *(u32x4*)(smemc + BUFB + flat * 16) = (u32x4){0u, 0u, 0u, 0u};
        }
    }

    f32x4 acc[4][8];
#pragma unroll
    for (int mi = 0; mi < 4; ++mi)
#pragma unroll
        for (int nf = 0; nf < 8; ++nf) acc[mi][nf] = (f32x4){0.f, 0.f, 0.f, 0.f};

    const f16* wHp = wHL;
    const f16* wLp = wHL + 589824;

    // prologue: DMA chunk 0 into buffer 0
#pragma unroll
    for (int w = 0; w < 7; ++w)
        if (srco[w] >= 0)
            __builtin_amdgcn_global_load_lds(AS1C(nhb + srco[w]),
                AS3(smemc + (w * 256 + (tid & ~63)) * 16), 16, 0, 0);
    __syncthreads();   // drains vmcnt -> buffer 0 ready

    for (int chunk = 0; chunk < 8; ++chunk) {
        // async-prefetch next chunk into the other buffer; barrier at loop end drains it
        if (chunk < 7) {
            const unsigned char* cb2 = nhb + (size_t)(chunk + 1) * HW * 128;
            int nb = ((chunk + 1) & 1) * BUFB;
#pragma unroll
            for (int w = 0; w < 7; ++w)
                if (srco[w] >= 0)
                    __builtin_amdgcn_global_load_lds(AS1C(cb2 + srco[w]),
                        AS3(smemc + nb + (w * 256 + (tid & ~63)) * 16), 16, 0, 0);
        }
        int cb_ = (chunk & 1) * BUFB;

        for (int kyx = 0; kyx < 9; ++kyx) {
            int ky = kyx / 3, kx = kyx % 3;
            f16x8 aH[4], aL[4];
#pragma unroll
            for (int mi = 0; mi < 4; ++mi) {
                int q = (2 * wm + (mi >> 1) + ky) * 34 + (mi & 1) * 16 + kx + lr;
                int sw = (q & 7) << 4;
                int rb = cb_ + q * 128;
                aH[mi] = *(const f16x8*)(smemc + rb + ((lg * 16) ^ sw));
                aL[mi] = *(const f16x8*)(smemc + rb + ((64 + lg * 16) ^ sw));
            }
            u32 kbase = (u32)(kyx * 32 + chunk * 4 + lg) * 256;
#pragma unroll
            for (int h = 0; h < 2; ++h) {
                f16x8 bH[4], bL[4];
#pragma unroll
                for (int j = 0; j < 4; ++j) {
                    int nf = h * 4 + j;
                    u32 ei = (kbase + (u32)(wn * 128 + nf * 16 + lr)) * 8;
                    bH[j] = *(const f16x8*)(wHp + ei);
                    bL[j] = *(const f16x8*)(wLp + ei);
                }
#pragma unroll
                for (int j = 0; j < 4; ++j) {
#pragma unroll
                    for (int mi = 0; mi < 4; ++mi) {
                        f32x4 c = acc[mi][h * 4 + j];
                        c = __builtin_amdgcn_mfma_f32_16x16x32_f16(aH[mi], bH[j], c, 0, 0, 0);
                        c = __builtin_amdgcn_mfma_f32_16x16x32_f16(aH[mi], bL[j], c, 0, 0, 0);
                        c = __builtin_amdgcn_mfma_f32_16x16x32_f16(aL[mi], bH[j], c, 0, 0, 0);
                        acc[mi][h * 4 + j] = c;
                    }
                }
            }
        }
        __syncthreads();   // drains prefetch DMA; all reads of current buffer done
    }

    // ---- epilogue: R7 VERBATIM (frozen head-sum numerics) ----
    for (int j = tid; j < 3840; j += 256) {
        int o = j >> 8, co = j & 255;
        smf[E_WH + j] = (o < 3) ? ow[o * 256 + co] : dw_[(o - 3) * 256 + co];
    }
    if (tid < 15) smf[E_HB + tid] = (tid < 3) ? ob[tid] : db_[tid - 3];
    for (int j = tid; j < 1920; j += 256) smf[E_PART + j] = 0.f;

    float cbv[8];
#pragma unroll
    for (int nf = 0; nf < 8; ++nf) cbv[nf] = cb[wn * 128 + nf * 16 + lr];
    __syncthreads();

#pragma unroll
    for (int mi = 0; mi < 4; ++mi)
#pragma unroll
        for (int nf = 0; nf < 8; ++nf)
#pragma unroll
            for (int e = 0; e < 4; ++e)
                acc[mi][nf][e] = fmaxf(acc[mi][nf][e] + cbv[nf], 0.f);

    for (int o = 0; o < 15; ++o) {
        float wv[8];
#pragma unroll
        for (int nf = 0; nf < 8; ++nf) wv[nf] = smf[E_WH + o * 256 + wn * 128 + nf * 16 + lr];
#pragma unroll
        for (int mi = 0; mi < 4; ++mi) {
#pragma unroll
            for (int e = 0; e < 4; ++e) {
                float s = 0.f;
#pragma unroll
                for (int nf = 0; nf < 8; ++nf) s = fmaf(wv[nf], acc[mi][nf][e], s);
                s += __shfl_xor(s, 1);
                s += __shfl_xor(s, 2);
                s += __shfl_xor(s, 4);
                s += __shfl_xor(s, 8);
                if (lr == 0)
                    atomicAdd(&smf[E_PART + (wm * 15 + o) * 64 + mi * 16 + lg * 4 + e], s);
            }
        }
    }
    __syncthreads();

    if ((l & 63) < 32) {
        int px = wn * 32 + (l & 31);
        int yy = 2 * wm + (px >> 5);
        int gx = tx0 + (px & 31);
        int gy = ty0 + yy;
        if (gx < W) {
            int aOff = (lvl == 0) ? 0 : (lvl == 1) ? 196608 : (lvl == 2) ? 245760 : (lvl == 3) ? 258048 : 261120;
            float size = (float)(32 << lvl);
            float stride = (float)(4 << lvl);
            float cxa = gx * stride, cya = gy * stride;
#pragma unroll
            for (int a = 0; a < 3; ++a) {
                float lgt = smf[E_PART + (wm * 15 + a) * 64 + px] + smf[E_HB + a];
                float dxv = smf[E_PART + (wm * 15 + 3 + a * 4 + 0) * 64 + px] + smf[E_HB + 3 + a * 4 + 0];
                float dyv = smf[E_PART + (wm * 15 + 3 + a * 4 + 1) * 64 + px] + smf[E_HB + 3 + a * 4 + 1];
                float dwv = smf[E_PART + (wm * 15 + 3 + a * 4 + 2) * 64 + px] + smf[E_HB + 3 + a * 4 + 2];
                float dhv = smf[E_PART + (wm * 15 + 3 + a * 4 + 3) * 64 + px] + smf[E_HB + 3 + a * 4 + 3];
                float r = (a == 0) ? 0.5f : (a == 1) ? 1.0f : 2.0f;
                float wa = sqrtf(size * size / r);
                float ha = wa * r;
                dwv = fminf(dwv, SCALE_CLAMP);
                dhv = fminf(dhv, SCALE_CLAMP);
                float cx = dxv * wa + cxa, cy = dyv * ha + cya;
                float w_ = expf(dwv) * wa, h_ = expf(dhv) * ha;
                float x1 = fminf(fmaxf(cx - 0.5f * w_, 0.f), 1024.f);
                float y1 = fminf(fmaxf(cy - 0.5f * h_, 0.f), 1024.f);
                float x2 = fminf(fmaxf(cx + 0.5f * w_, 0.f), 1024.f);
                float y2 = fminf(fmaxf(cy + 0.5f * h_, 0.f), 1024.f);
                double sc = 1.0 / (1.0 + exp(-(double)lgt));
                u32 bits = __float_as_uint((float)sc);
                int gi = aOff + (gy * W + gx) * 3 + a;
                scoreb[(size_t)n * NA + gi] = bits;
                float* bp = boxes + ((size_t)n * NA + gi) * 4;
                bp[0] = x1; bp[1] = y1; bp[2] = x2; bp[3] = y2;
            }
        }
    }
}

// ---- fallback conv (R4 verbatim): NCHW staging + T14 prefetch ----
__global__ __launch_bounds__(256, 2) void k_conv_legacy(
    const float* __restrict__ p2, const float* __restrict__ p3,
    const float* __restrict__ p4, const float* __restrict__ p5,
    const float* __restrict__ p6, const f16* __restrict__ wHL,
    const float* __restrict__ cb, const float* __restrict__ ow,
    const float* __restrict__ ob, const float* __restrict__ dw_,
    const float* __restrict__ db_, u32* __restrict__ scoreb,
    float* __restrict__ boxes)
{
    __shared__ __align__(16) float smf[6528];
    char* smemc = (char*)smf;

    int tid = threadIdx.x;
    int bid = blockIdx.x;
    int n = bid / NBLK_IMG;
    int tb = bid % NBLK_IMG;
    int lvl, t0;
    if      (tb < 512) { lvl = 0; t0 = tb;       }
    else if (tb < 640) { lvl = 1; t0 = tb - 512; }
    else if (tb < 672) { lvl = 2; t0 = tb - 640; }
    else if (tb < 680) { lvl = 3; t0 = tb - 672; }
    else               { lvl = 4; t0 = tb - 680; }
    int H = 256 >> lvl, W = H;
    int HW = H * W;
    int xtiles = (W >= 32) ? (W >> 5) : 1;
    int xt = t0 % xtiles, yt = t0 / xtiles;
    int tx0 = xt * 32, ty0 = yt * 4;
    const float* in = (lvl == 0) ? p2 : (lvl == 1) ? p3 : (lvl == 2) ? p4 : (lvl == 3) ? p5 : p6;
    in += (size_t)n * 256 * HW;

    int l = tid & 63;
    int wid = tid >> 6;
    int wm = wid >> 1, wn = wid & 1;
    int lr = l & 15;
    int lg = l >> 4;

    int off[13];
#pragma unroll
    for (int w = 0; w < 13; ++w) {
        int idx = w * 256 + tid;
        int ci2 = idx / 204, p = idx % 204;
        int dy = p / 34, dx = p % 34;
        int y = ty0 + dy - 1, x = tx0 + dx - 1;
        bool inb = (idx < 3264) && y >= 0 && y < H && x >= 0 && x < W;
        off[w] = inb ? (ci2 * 2 * HW + y * W + x) : -1;
    }

    float rv0[13], rv1[13];
#pragma unroll
    for (int w = 0; w < 13; ++w) {
        rv0[w] = 0.f; rv1[w] = 0.f;
        if (off[w] >= 0) { const float* gp = in + off[w]; rv0[w] = gp[0]; rv1[w] = gp[HW]; }
    }

    f32x4 acc[4][8];
#pragma unroll
    for (int mi = 0; mi < 4; ++mi)
#pragma unroll
        for (int nf = 0; nf < 8; ++nf) acc[mi][nf] = (f32x4){0.f, 0.f, 0.f, 0.f};

    const f16* wHp = wHL;
    const f16* wLp = wHL + 589824;

    for (int chunk = 0; chunk < 8; ++chunk) {
        __syncthreads();
#pragma unroll
        for (int w = 0; w < 13; ++w) {
            int idx = w * 256 + tid;
            if (idx < 3264) {
                int ci2 = idx / 204, p = idx % 204;
                f16 h0 = (f16)rv0[w], h1 = (f16)rv1[w];
                f16 e0 = (f16)(rv0[w] - (float)h0), e1 = (f16)(rv1[w] - (float)h1);
                u32 hp = ((u32)__builtin_bit_cast(unsigned short, h1) << 16) |
                          (u32)__builtin_bit_cast(unsigned short, h0);
                u32 lp = ((u32)__builtin_bit_cast(unsigned short, e1) << 16) |
                          (u32)__builtin_bit_cast(unsigned short, e0);
                int sw = (p & 7) << 4;
                int rb = p * 128;
                *(u32*)(smemc + rb + ((ci2 * 4) ^ sw)) = hp;
                *(u32*)(smemc + rb + ((64 + ci2 * 4) ^ sw)) = lp;
            }
        }
        if (chunk < 7) {
            const float* cbase = in + (size_t)(chunk + 1) * 32 * HW;
#pragma unroll
            for (int w = 0; w < 13; ++w) {
                rv0[w] = 0.f; rv1[w] = 0.f;
                if (off[w] >= 0) { const float* gp = cbase + off[w]; rv0[w] = gp[0]; rv1[w] = gp[HW]; }
            }
        }
        __syncthreads();

        for (int kyx = 0; kyx < 9; ++kyx) {
            int ky = kyx / 3, kx = kyx % 3;
            f16x8 aH[4], aL[4];
#pragma unroll
            for (int mi = 0; mi < 4; ++mi) {
                int q = (2 * wm + (mi >> 1) + ky) * 34 + (mi & 1) * 16 + kx + lr;
                int sw = (q & 7) << 4;
                int rb = q * 128;
                aH[mi] = *(const f16x8*)(smemc + rb + ((lg * 16) ^ sw));
                aL[mi] = *(const f16x8*)(smemc + rb + ((64 + lg * 16) ^ sw));
            }
            u32 kbase = (u32)(kyx * 32 + chunk * 4 + lg) * 256;
#pragma unroll
            for (int h = 0; h < 2; ++h) {
                f16x8 bH[4], bL[4];
#pragma unroll
                for (int j = 0; j < 4; ++j) {
                    int nf = h * 4 + j;
                    u32 ei = (kbase + (u32)(wn * 128 + nf * 16 + lr)) * 8;
                    bH[j] = *(const f16x8*)(wHp + ei);
                    bL[j] = *(const f16x8*)(wLp + ei);
                }
#pragma unroll
                for (int j = 0; j < 4; ++j) {
#pragma unroll
                    for (int mi = 0; mi < 4; ++mi) {
                        f32x4 c = acc[mi][h * 4 + j];
                        c = __builtin_amdgcn_mfma_f32_16x16x32_f16(aH[mi], bH[j], c, 0, 0, 0);
                        c = __builtin_amdgcn_mfma_f32_16x16x32_f16(aH[mi], bL[j], c, 0, 0, 0);
                        c = __builtin_amdgcn_mfma_f32_16x16x32_f16(aL[mi], bH[j], c, 0, 0, 0);
                        acc[mi][h * 4 + j] = c;
                    }
                }
            }
        }
    }

    __syncthreads();
    for (int j = tid; j < 3840; j += 256) {
        int o = j >> 8, co = j & 255;
        smf[E_WH + j] = (o < 3) ? ow[o * 256 + co] : dw_[(o - 3) * 256 + co];
    }
    if (tid < 15) smf[E_HB + tid] = (tid < 3) ? ob[tid] : db_[tid - 3];
    for (int j = tid; j < 1920; j += 256) smf[E_PART + j] = 0.f;

    float cbv[8];
#pragma unroll
    for (int nf = 0; nf < 8; ++nf) cbv[nf] = cb[wn * 128 + nf * 16 + lr];
    __syncthreads();

#pragma unroll
    for (int mi = 0; mi < 4; ++mi)
#pragma unroll
        for (int nf = 0; nf < 8; ++nf)
#pragma unroll
            for (int e = 0; e < 4; ++e)
                acc[mi][nf][e] = fmaxf(acc[mi][nf][e] + cbv[nf], 0.f);

    for (int o = 0; o < 15; ++o) {
        float wv[8];
#pragma unroll
        for (int nf = 0; nf < 8; ++nf) wv[nf] = smf[E_WH + o * 256 + wn * 128 + nf * 16 + lr];
#pragma unroll
        for (int mi = 0; mi < 4; ++mi) {
#pragma unroll
            for (int e = 0; e < 4; ++e) {
                float s = 0.f;
#pragma unroll
                for (int nf = 0; nf < 8; ++nf) s = fmaf(wv[nf], acc[mi][nf][e], s);
                s += __shfl_xor(s, 1);
                s += __shfl_xor(s, 2);
                s += __shfl_xor(s, 4);
                s += __shfl_xor(s, 8);
                if (lr == 0)
                    atomicAdd(&smf[E_PART + (wm * 15 + o) * 64 + mi * 16 + lg * 4 + e], s);
            }
        }
    }
    __syncthreads();

    if ((l & 63) < 32) {
        int px = wn * 32 + (l & 31);
        int yy = 2 * wm + (px >> 5);
        int gx = tx0 + (px & 31);
        int gy = ty0 + yy;
        if (gx < W) {
            int aOff = (lvl == 0) ? 0 : (lvl == 1) ? 196608 : (lvl == 2) ? 245760 : (lvl == 3) ? 258048 : 261120;
            float size = (float)(32 << lvl);
            float stride = (float)(4 << lvl);
            float cxa = gx * stride, cya = gy * stride;
#pragma unroll
            for (int a = 0; a < 3; ++a) {
                float lgt = smf[E_PART + (wm * 15 + a) * 64 + px] + smf[E_HB + a];
                float dxv = smf[E_PART + (wm * 15 + 3 + a * 4 + 0) * 64 + px] + smf[E_HB + 3 + a * 4 + 0];
                float dyv = smf[E_PART + (wm * 15 + 3 + a * 4 + 1) * 64 + px] + smf[E_HB + 3 + a * 4 + 1];
                float dwv = smf[E_PART + (wm * 15 + 3 + a * 4 + 2) * 64 + px] + smf[E_HB + 3 + a * 4 + 2];
                float dhv = smf[E_PART + (wm * 15 + 3 + a * 4 + 3) * 64 + px] + smf[E_HB + 3 + a * 4 + 3];
                float r = (a == 0) ? 0.5f : (a == 1) ? 1.0f : 2.0f;
                float wa = sqrtf(size * size / r);
                float ha = wa * r;
                dwv = fminf(dwv, SCALE_CLAMP);
                dhv = fminf(dhv, SCALE_CLAMP);
                float cx = dxv * wa + cxa, cy = dyv * ha + cya;
                float w_ = expf(dwv) * wa, h_ = expf(dhv) * ha;
                float x1 = fminf(fmaxf(cx - 0.5f * w_, 0.f), 1024.f);
                float y1 = fminf(fmaxf(cy - 0.5f * h_, 0.f), 1024.f);
                float x2 = fminf(fmaxf(cx + 0.5f * w_, 0.f), 1024.f);
                float y2 = fminf(fmaxf(cy + 0.5f * h_, 0.f), 1024.f);
                double sc = 1.0 / (1.0 + exp(-(double)lgt));
                u32 bits = __float_as_uint((float)sc);
                int gi = aOff + (gy * W + gx) * 3 + a;
                scoreb[(size_t)n * NA + gi] = bits;
                float* bp = boxes + ((size_t)n * NA + gi) * 4;
                bp[0] = x1; bp[1] = y1; bp[2] = x2; bp[3] = y2;
            }
        }
    }
}

// -------------------- coarse histogram (b>>20), LDS-privatized --------------------
__global__ __launch_bounds__(256) void k_histc(const u32* __restrict__ scoreb,
                                               u32* __restrict__ histc) {
    __shared__ u32 lh[4096];
    for (int j = threadIdx.x; j < 4096; j += 256) lh[j] = 0;
    __syncthreads();
    int n = blockIdx.x >> 6;
    int blk = blockIdx.x & 63;
    const u32* sb = scoreb + (size_t)n * NA;
    for (int i = blk * 256 + threadIdx.x; i < NA; i += 64 * 256)
        atomicAdd(&lh[sb[i] >> 20], 1u);
    __syncthreads();
    for (int j = threadIdx.x; j < 4096; j += 256) {
        u32 v = lh[j];
        if (v) atomicAdd(&histc[n * 4096 + j], v);
    }
}

// -------------------- find coarse crossing bin C* + countAbove --------------------
__global__ void k_scanc(const u32* __restrict__ histc, u32* __restrict__ meta) {
    int n = blockIdx.x, tid = threadIdx.x;
    __shared__ u32 cs[256];
    u32 s = 0;
    for (int j = 0; j < 16; ++j) s += histc[n * 4096 + (4095 - (tid * 16 + j))];
    cs[tid] = s;
    __syncthreads();
    if (tid == 0) {
        u32 cum = 0;
        for (int t = 0; t < 256; ++t) {
            if (cum + cs[t] >= 1000u) {
                u32 c2 = cum;
                for (int d = t * 16;; ++d) {
                    int bin = 4095 - d;
                    u32 h = histc[n * 4096 + bin];
                    if (c2 + h >= 1000u) { meta[n * 4 + 1] = (u32)bin; meta[n * 4 + 2] = c2; break; }
                    c2 += h;
                }
                break;
            }
            cum += cs[t];
        }
    }
}

// -------------------- exact 16-sub-bin refine inside C* --------------------
__global__ void k_fine(const u32* __restrict__ scoreb, const u32* __restrict__ meta,
                       u32* __restrict__ fineh) {
    __shared__ u32 lf[32];
    if (threadIdx.x < 32) lf[threadIdx.x] = 0;
    __syncthreads();
    u32 C0 = meta[1], C1 = meta[5];
    int stridex = gridDim.x * blockDim.x;
    for (int i = blockIdx.x * blockDim.x + threadIdx.x; i < 2 * NA; i += stridex) {
        u32 b = scoreb[i];
        int n = (i >= NA);
        if ((b >> 20) == (n ? C1 : C0)) atomicAdd(&lf[n * 16 + ((b >> 16) & 15)], 1u);
    }
    __syncthreads();
    if (threadIdx.x < 32) {
        u32 v = lf[threadIdx.x];
        if (v) atomicAdd(&fineh[threadIdx.x], v);
    }
}

// -------------------- exact 16-bit threshold T --------------------
__global__ void k_scanf(const u32* __restrict__ fineh, u32* __restrict__ meta) {
    int n = threadIdx.x;
    if (n < 2) {
        u32 cum = meta[n * 4 + 2];
        u32 C = meta[n * 4 + 1];
        u32 T = C << 4;
        for (int f = 15; f >= 0; --f) {
            cum += fineh[n * 16 + f];
            if (cum >= 1000u) { T = (C << 4) | (u32)f; break; }
        }
        meta[n * 4] = T;
    }
}

// -------------------- compact candidates >= threshold bin --------------------
__global__ void k_compact(const u32* __restrict__ scoreb, const u32* __restrict__ meta,
                          u32* __restrict__ cnt, u64* __restrict__ cand) {
    int stridex = gridDim.x * blockDim.x;
    for (int i = blockIdx.x * blockDim.x + threadIdx.x; i < 2 * NA; i += stridex) {
        u32 b = scoreb[i];
        int n = (i >= NA);
        u32 T = meta[n * 4];
        if ((b >> 16) >= T) {
            u32 p = atomicAdd(&cnt[n], 1u);
            if (p < CAP)
                cand[n * CAP + p] = ((u64)(~b) << 32) | (u32)(i - n * NA);
        }
    }
}

// -------------------- bitonic sort candidates, gather top-1000 boxes --------------------
__global__ __launch_bounds__(1024) void k_sort(const u64* __restrict__ cand,
                                               const u32* __restrict__ cnt,
                                               const float* __restrict__ boxes,
                                               float* __restrict__ topbox) {
    __shared__ u64 a[CAP];
    int n = blockIdx.x, tid = threadIdx.x;
    u32 C = cnt[n]; if (C > CAP) C = CAP;
    for (int i = tid; i < CAP; i += 1024)
        a[i] = (i < (int)C) ? cand[n * CAP + i] : ~0ULL;
    __syncthreads();
    for (int k = 2; k <= CAP; k <<= 1) {
        for (int j = k >> 1; j > 0; j >>= 1) {
            for (int i = tid; i < CAP; i += 1024) {
                int l = i ^ j;
                if (l > i) {
                    u64 x = a[i], y = a[l];
                    bool up = ((i & k) == 0);
                    if ((x > y) == up) { a[i] = y; a[l] = x; }
                }
            }
            __syncthreads();
        }
    }
    for (int r = tid; r < 1000; r += 1024) {
        u32 idx = (u32)(a[r] & 0xFFFFFFFFu);
        const float* bp = boxes + ((size_t)n * NA + idx) * 4;
        float* tp = topbox + (n * 1000 + r) * 4;
        tp[0] = bp[0]; tp[1] = bp[1]; tp[2] = bp[2]; tp[3] = bp[3];
    }
}

// -------------------- NMS suppression bitmasks --------------------
__global__ __launch_bounds__(256) void k_mask(const float* __restrict__ topbox,
                                              u64* __restrict__ mask) {
    __shared__ float4 lb[1000];
    int n = blockIdx.x >> 2, sub = blockIdx.x & 3;
    for (int e = threadIdx.x; e < 1000; e += 256)
        lb[e] = ((const float4*)topbox)[n * 1000 + e];
    __syncthreads();
    int i = sub * 256 + threadIdx.x;
    if (i >= 1000) return;
    float4 b = lb[i];
    float area = (b.z - b.x) * (b.w - b.y);
    u64* mrow = mask + (size_t)(n * 1000 + i) * 16;
    for (int w = 0; w < 16; ++w) {
        u64 bits = 0;
        int j0 = w * 64;
        int jmax = 1000 - j0; if (jmax > 64) jmax = 64;
        for (int jb = 0; jb < jmax; ++jb) {
            int j = j0 + jb;
            if (j > i) {
                float4 c = lb[j];
                float ix1 = fmaxf(b.x, c.x), iy1 = fmaxf(b.y, c.y);
                float ix2 = fminf(b.z, c.z), iy2 = fminf(b.w, c.w);
                float iw = fmaxf(ix2 - ix1, 0.f), ih = fmaxf(iy2 - iy1, 0.f);
                float inter = iw * ih;
                float areac = (c.z - c.x) * (c.w - c.y);
                float iou = inter / fmaxf(area + areac - inter, 1e-6f);
                if (iou > 0.7f) bits |= (1ULL << jb);
            }
        }
        mrow[w] = bits;
    }
}

// -------------------- sequential sweep + stable partition + output --------------------
__global__ __launch_bounds__(256) void k_final(const float* __restrict__ topbox,
                                               const u64* __restrict__ mask,
                                               float* __restrict__ out) {
    __shared__ u64 kw[16];
    __shared__ u32 PL[17];
    int n = blockIdx.x, tid = threadIdx.x;
    if (tid < 64) {
        int lane = tid;
        u64 keep = 0;
        if (lane < 16) keep = (lane < 15) ? ~0ULL : ((1ULL << 40) - 1);
        const u64* mb = mask + (size_t)n * 16000;
        u64 rcur = mb[lane & 15];
        for (int i = 0; i < 1000; ++i) {
            u64 rnext = (i + 1 < 1000) ? mb[(size_t)(i + 1) * 16 + (lane & 15)] : 0ULL;
            int w = i >> 6;
            u64 kb = __shfl(keep, w, 64);
            if ((kb >> (i & 63)) & 1ULL) {
                if (lane < 16) keep &= ~rcur;
            }
            rcur = rnext;
        }
        if (lane < 16) kw[lane] = keep;
    }
    __syncthreads();
    if (tid == 0) {
        u32 c = 0;
        for (int w = 0; w < 16; ++w) { PL[w] = c; c += (u32)__popcll(kw[w]); }
        PL[16] = c;
    }
    __syncthreads();
    u32 NK = PL[16];
    for (int i = tid; i < 1000; i += 256) {
        int w = i >> 6, b = i & 63;
        u64 word = kw[w];
        bool kept = (word >> b) & 1ULL;
        u32 kb4 = PL[w] + (u32)__popcll(word & ((1ULL << b) - 1ULL));
        u32 pos = kept ? kb4 : NK + (u32)i - kb4;
        const float* bp = topbox + (n * 1000 + i) * 4;
        float x1 = kept ? bp[0] : 0.f;
        float y1 = kept ? bp[1] : 0.f;
        float x2 = kept ? bp[2] : 0.f;
        float y2 = kept ? bp[3] : 0.f;
        size_t rrow = (size_t)n * 1000 + pos;
        out[rrow * 5 + 0] = 0.f;
        out[rrow * 5 + 1] = x1; out[rrow * 5 + 2] = y1;
        out[rrow * 5 + 3] = x2; out[rrow * 5 + 4] = y2;
        float* dp = out + 10000 + rrow * 4;
        dp[0] = x1; dp[1] = y1; dp[2] = x2; dp[3] = y2;
    }
}

extern "C" void kernel_launch(void* const* d_in, const int* in_sizes, int n_in,
                              void* d_out, int out_size, void* d_ws, size_t ws_size,
                              hipStream_t stream) {
    const float* p2 = (const float*)d_in[0];
    const float* p3 = (const float*)d_in[1];
    const float* p4 = (const float*)d_in[2];
    const float* p5 = (const float*)d_in[3];
    const float* p6 = (const float*)d_in[4];
    const float* conv_w = (const float*)d_in[5];
    const float* conv_b = (const float*)d_in[6];
    const float* obj_w = (const float*)d_in[7];
    const float* obj_b = (const float*)d_in[8];
    const float* delta_w = (const float*)d_in[9];
    const float* delta_b = (const float*)d_in[10];
    char* ws = (char*)d_ws;

    f16*   wHL    = (f16*)  (ws + WT_OFF);
    float* boxes  = (float*)(ws + BOX_OFF);
    u32*   scoreb = (u32*)  (ws + SB_OFF);
    u32*   histc  = (u32*)  (ws + HIST_OFF);
    u32*   fineh  = (u32*)  (ws + FINE_OFF);
    u32*   meta   = (u32*)  (ws + META_OFF);
    u32*   cnt    = meta + 8;
    u64*   cand   = (u64*)  (ws + CAND_OFF);
    float* topbox = (float*)(ws + TOP_OFF);
    u64*   mask   = (u64*)  (ws + MASK_OFF);

    hipMemsetAsync(ws + HIST_OFF, 0, 32768 + 128, stream);
    hipMemsetAsync(ws + META_OFF, 0, 64, stream);

    k_wprep<<<2304, 256, 0, stream>>>(conv_w, wHL);

    if (ws_size >= WS_NEED) {
        unsigned char* nh = (unsigned char*)(ws + NH_OFF);
        k_nhwc<<<5456, 256, 0, stream>>>(p2, p3, p4, p5, p6, nh);
        k_conv_nh<<<2 * NBLK_IMG, 256, 0, stream>>>(nh, wHL, conv_b,
                                                    obj_w, obj_b, delta_w, delta_b,
                                                    scoreb, boxes);
    } else {
        k_conv_legacy<<<2 * NBLK_IMG, 256, 0, stream>>>(p2, p3, p4, p5, p6, wHL, conv_b,
                                                        obj_w, obj_b, delta_w, delta_b,
                                                        scoreb, boxes);
    }
    k_histc<<<128, 256, 0, stream>>>(scoreb, histc);
    k_scanc<<<2, 256, 0, stream>>>(histc, meta);
    k_fine<<<512, 256, 0, stream>>>(scoreb, meta, fineh);
    k_scanf<<<1, 64, 0, stream>>>(fineh, meta);
    k_compact<<<1024, 256, 0, stream>>>(scoreb, meta, cnt, cand);
    k_sort<<<2, 1024, 0, stream>>>(cand, cnt, boxes, topbox);
    k_mask<<<8, 256, 0, stream>>>(topbox, mask);
    k_final<<<2, 256, 0, stream>>>(topbox, mask, (float*)d_out);
    (void)in_sizes; (void)n_in; (void)out_size; (void)ws_size;
}